// Round 4
// baseline (33.617 us; speedup 1.0000x reference)
//
#include <hip/hip_runtime.h>

// GatedBlock: B=16, C=128, T=64, F=128, S=62, dilation=2, fp32 in/out.
// out[b,c,s,f] = (tanh(x0*wt0+x1*wt1+bt) * sigmoid(x0*ws0+x1*ws1+bs)
//                 + sum_t x[b,c,t,f]*w_res[s,t] + b_res[s]) * w_out[c] + b_out[c]
//
// Round 4: single dispatch. Each block (one per (b,c)) builds its own bf16
// A-fragments from global w_res (L2-broadcast), stages the 32KB x tile in LDS
// (fp32, stride 130 -> 2-way-free banks), runs 16x16x32 bf16 MFMA for the
// einsum (b_res folded into C-init), recomputes the gate in fp32 from LDS.
// Epilogue: 6 LDS taps per (rt,ct) (x1[r]=x0[r+2] reuse) and a single rcp:
// tanh(a)*sigmoid(b) = (e2-1)*rcp((e2+1)*(1+exp(-b))).

typedef __attribute__((ext_vector_type(8)))  short short8;
typedef __attribute__((ext_vector_type(4)))  float f32x4;
typedef __attribute__((ext_vector_type(4)))  int   i32x4;
typedef __attribute__((ext_vector_type(2)))  float f32x2;

constexpr int Bc = 16, Cc = 128, Tc = 64, Fc = 128, Sc = 62, DIL = 2;
constexpr int LDSW    = 130;   // floats per LDS row (520 B)
constexpr int LDSROWS = 66;    // 64 data rows + 2 pad rows (dead tail reads stay in-bounds)

__device__ inline unsigned cvt_pk_bf16(float lo, float hi) {
    unsigned r;
    asm("v_cvt_pk_bf16_f32 %0, %1, %2" : "=v"(r) : "v"(lo), "v"(hi));
    return r;   // low16 = bf16(lo), high16 = bf16(hi), RNE
}

__global__ __launch_bounds__(256, 4)
void gated_mfma_kernel(const float* __restrict__ x,
                       const float* __restrict__ w_tanh,
                       const float* __restrict__ b_tanh,
                       const float* __restrict__ w_sig,
                       const float* __restrict__ b_sig,
                       const float* __restrict__ w_out,
                       const float* __restrict__ b_out,
                       const float* __restrict__ w_res,
                       const float* __restrict__ b_res,
                       float* __restrict__ out)
{
    __shared__ float lds[LDSROWS * LDSW];     // 34320 B

    const int bc   = blockIdx.x;              // (b,c) pair
    const int c    = bc & (Cc - 1);
    const int tid  = threadIdx.x;
    const int lane = tid & 63;
    const int w    = tid >> 6;                // wave 0..3 -> col-tiles 2w,2w+1
    const int g    = lane >> 4;               // lane group 0..3
    const int r16  = lane & 15;

    const float wt0 = w_tanh[2 * c + 0], wt1 = w_tanh[2 * c + 1], bt = b_tanh[c];
    const float ws0 = w_sig[2 * c + 0],  ws1 = w_sig[2 * c + 1],  bs = b_sig[c];
    const float wo  = w_out[c],          bo  = b_out[c];

    // ---- stage x tile (fp32) into LDS, coalesced dwordx4 ----
    const float* xp = x + (size_t)bc * (Tc * Fc);
#pragma unroll
    for (int i = 0; i < 8; ++i) {
        const int o   = tid * 4 + i * 1024;   // flat float offset, 16B-aligned
        const int t   = o >> 7;
        const int col = o & 127;
        const f32x4 v = *(const f32x4*)(xp + o);
        float* d = lds + t * LDSW + col;      // rows 8B-aligned -> two b64 writes
        *(f32x2*)(d + 0) = f32x2{v.x, v.y};
        *(f32x2*)(d + 2) = f32x2{v.z, v.w};
    }

    // ---- A fragments: bf16(w_res) built per block from global (L2-hot 16KB).
    // Layout (matches verified round-3 packing): row = 16*rt + r16,
    // k = 32*kt + 8*g + [0..7], regs pack (k,k+1) pairs via cvt_pk.
    short8 A[4][2];
#pragma unroll
    for (int rt = 0; rt < 4; ++rt) {
        const int row = 16 * rt + r16;
        const bool ok = row < Sc;
        const float* wr = w_res + row * Tc + 8 * g;
#pragma unroll
        for (int kt = 0; kt < 2; ++kt) {
            f32x4 v0 = f32x4{0.f, 0.f, 0.f, 0.f};
            f32x4 v1 = f32x4{0.f, 0.f, 0.f, 0.f};
            if (ok) {
                v0 = *(const f32x4*)(wr + 32 * kt);
                v1 = *(const f32x4*)(wr + 32 * kt + 4);
            }
            const unsigned p0 = cvt_pk_bf16(v0.x, v0.y);
            const unsigned p1 = cvt_pk_bf16(v0.z, v0.w);
            const unsigned p2 = cvt_pk_bf16(v1.x, v1.y);
            const unsigned p3 = cvt_pk_bf16(v1.z, v1.w);
            A[rt][kt] = __builtin_bit_cast(short8,
                          i32x4{(int)p0, (int)p1, (int)p2, (int)p3});
        }
    }

    // ---- acc init = b_res[row] (C-operand of MFMA); clamp tail (masked rows unused)
    f32x4 acc[4][2];
#pragma unroll
    for (int rt = 0; rt < 4; ++rt) {
        f32x4 bv;
#pragma unroll
        for (int j = 0; j < 4; ++j) {
            const int idx = 16 * rt + 4 * g + j;
            bv[j] = b_res[idx < Sc ? idx : Sc - 1];
        }
        acc[rt][0] = bv;
        acc[rt][1] = bv;
    }

    __syncthreads();

    // ---- MFMA: 2 K-tiles x 2 col-tiles x 4 row-tiles ----
    const int col0 = 32 * w + r16;
#pragma unroll
    for (int kt = 0; kt < 2; ++kt) {
        short8 Bf[2];
#pragma unroll
        for (int ct = 0; ct < 2; ++ct) {
            const float* bp = lds + (32 * kt + 8 * g) * LDSW + col0 + 16 * ct;
            const unsigned p0 = cvt_pk_bf16(bp[0 * LDSW], bp[1 * LDSW]);
            const unsigned p1 = cvt_pk_bf16(bp[2 * LDSW], bp[3 * LDSW]);
            const unsigned p2 = cvt_pk_bf16(bp[4 * LDSW], bp[5 * LDSW]);
            const unsigned p3 = cvt_pk_bf16(bp[6 * LDSW], bp[7 * LDSW]);
            Bf[ct] = __builtin_bit_cast(short8, i32x4{(int)p0, (int)p1, (int)p2, (int)p3});
        }
#pragma unroll
        for (int rt = 0; rt < 4; ++rt)
#pragma unroll
            for (int ct = 0; ct < 2; ++ct)
                acc[rt][ct] = __builtin_amdgcn_mfma_f32_16x16x32_bf16(
                    A[rt][kt], Bf[ct], acc[rt][ct], 0, 0, 0);
    }

    // ---- epilogue: gate (fp32 from LDS, 6 taps per (rt,ct)) + store ----
    float* op = out + (size_t)bc * (Sc * Fc);
#pragma unroll
    for (int rt = 0; rt < 4; ++rt) {
        const int r0 = 16 * rt + 4 * g;
#pragma unroll
        for (int ct = 0; ct < 2; ++ct) {
            const int col = col0 + 16 * ct;
            const float* bp = lds + r0 * LDSW + col;
            const float t0 = bp[0 * LDSW];
            const float t1 = bp[1 * LDSW];
            const float t2 = bp[2 * LDSW];
            const float t3 = bp[3 * LDSW];
            const float t4 = bp[4 * LDSW];   // rows r0+4, r0+5: pad rows for the
            const float t5 = bp[5 * LDSW];   // rt=3,g=3 tail — values unused there

#define GATE_OUT(reg, xa, xb)                                                     \
            if (r0 + (reg) < Sc) {                                                \
                const float xt  = fmaf((xa), wt0, fmaf((xb), wt1, bt));           \
                const float xsg = fmaf((xa), ws0, fmaf((xb), ws1, bs));           \
                const float e2  = __expf(2.0f * xt);                              \
                const float em  = __expf(-xsg);                                   \
                const float gate = (e2 - 1.0f) *                                  \
                    __builtin_amdgcn_rcpf((e2 + 1.0f) * (1.0f + em));             \
                op[(r0 + (reg)) * Fc + col] =                                     \
                    fmaf(gate + acc[rt][ct][reg], wo, bo);                        \
            }
            GATE_OUT(0, t0, t2)
            GATE_OUT(1, t1, t3)
            GATE_OUT(2, t2, t4)
            GATE_OUT(3, t3, t5)
#undef GATE_OUT
        }
    }
}

extern "C" void kernel_launch(void* const* d_in, const int* in_sizes, int n_in,
                              void* d_out, int out_size, void* d_ws, size_t ws_size,
                              hipStream_t stream)
{
    const float* x      = (const float*)d_in[0];
    const float* w_tanh = (const float*)d_in[1];
    const float* b_tanh = (const float*)d_in[2];
    const float* w_sig  = (const float*)d_in[3];
    const float* b_sig  = (const float*)d_in[4];
    const float* w_out  = (const float*)d_in[5];
    const float* b_out  = (const float*)d_in[6];
    const float* w_res  = (const float*)d_in[7];
    const float* b_res  = (const float*)d_in[8];
    // d_in[9] = dilation (==2) -> compile-time DIL.

    float* out = (float*)d_out;

    gated_mfma_kernel<<<Bc * Cc, 256, 0, stream>>>(
        x, w_tanh, b_tanh, w_sig, b_sig, w_out, b_out, w_res, b_res, out);
}

// Round 7
// 27.573 us; speedup vs baseline: 1.2192x; 1.2192x over previous
//
#include <hip/hip_runtime.h>

// GatedBlock: B=16, C=128, T=64, F=128, S=62, dilation=2, fp32 in/out.
// out[b,c,s,f] = (tanh(x0*wt0+x1*wt1+bt) * sigmoid(x0*ws0+x1*ws1+bs)
//                 + sum_t x[b,c,t,f]*w_res[s,t] + b_res[s]) * w_out[c] + b_out[c]
//
// Round 7: bf16 TRANSPOSED x tile in LDS (xT[f][t^swz], LDSTW=72) + shared
// bf16 A-fragments (round-6 explicit slot scheme — verified; round 6's failure
// was LDSW=126<128 row overflow, fixed by this redesign).
//  - LDS 26.6KB -> 5-6 blocks/CU (was 4 at 34.8KB)
//  - B-frag = one aligned ds_read_b128 (8 consecutive k at fixed f); swizzle
//    t~ = t ^ 8*((f>>2)&3) preserves ascending-k order (address permutation),
//    so MFMA A/B convention is identical to the passing round-4 kernel.
//  - epilogue taps: 2 x ds_read_b64 bf16 per (rt,ct)
//  - stage: 8t x 4f block per thread, in-register repack, 4 conflict-free
//    ds_write_b128 (bank bases {0,4,...,28}, 8 accesses/bank = b128 minimum)

typedef __attribute__((ext_vector_type(8)))  short short8;
typedef __attribute__((ext_vector_type(4)))  float f32x4;
typedef __attribute__((ext_vector_type(4)))  int   i32x4;
typedef __attribute__((ext_vector_type(2)))  int   i32x2;

constexpr int Bc = 16, Cc = 128, Tc = 64, Fc = 128, Sc = 62, DIL = 2;
constexpr int LDSTW    = 72;                  // bf16 elems per xT f-row (mult of 8)
constexpr int XT_BYTES = Fc * LDSTW * 2;      // 18432
constexpr int A_BYTES  = 8 * 64 * 16;         // 8192
constexpr int LDS_TOT  = XT_BYTES + A_BYTES;  // 26624

__device__ inline unsigned cvt_pk_bf16(float lo, float hi) {
    unsigned r;
    asm("v_cvt_pk_bf16_f32 %0, %1, %2" : "=v"(r) : "v"(lo), "v"(hi));
    return r;   // low16 = bf16(lo), high16 = bf16(hi), RNE
}

__device__ inline float bf16_lo(int u) { return __uint_as_float(((unsigned)u) << 16); }
__device__ inline float bf16_hi(int u) { return __uint_as_float(((unsigned)u) & 0xFFFF0000u); }

__global__ __launch_bounds__(256, 5)
void gated_mfma_kernel(const float* __restrict__ x,
                       const float* __restrict__ w_tanh,
                       const float* __restrict__ b_tanh,
                       const float* __restrict__ w_sig,
                       const float* __restrict__ b_sig,
                       const float* __restrict__ w_out,
                       const float* __restrict__ b_out,
                       const float* __restrict__ w_res,
                       const float* __restrict__ b_res,
                       float* __restrict__ out)
{
    __shared__ i32x4 smem[LDS_TOT / 16];
    char* lds_base = (char*)smem;              // xT: [0, 18432)
    char* lds_a    = lds_base + XT_BYTES;      // A-frags: [18432, 26624)

    const int bc   = blockIdx.x;               // (b,c) pair
    const int c    = bc & (Cc - 1);
    const int tid  = threadIdx.x;
    const int lane = tid & 63;
    const int w    = tid >> 6;                 // wave 0..3 -> col-tiles 2w,2w+1
    const int g    = lane >> 4;                // lane group 0..3
    const int r16  = lane & 15;

    const float wt0 = w_tanh[2 * c + 0], wt1 = w_tanh[2 * c + 1], bt = b_tanh[c];
    const float ws0 = w_sig[2 * c + 0],  ws1 = w_sig[2 * c + 1],  bs = b_sig[c];
    const float wo  = w_out[c],          bo  = b_out[c];

    // ---- stage x: thread (fq,tg) loads 8t x 4f block, coalesced dwordx4 ----
    const int fq = tid & 31;                   // f = 4*fq .. 4*fq+3
    const int tg = tid >> 5;                   // t = 8*tg .. 8*tg+7
    const float* xp = x + (size_t)bc * (Tc * Fc);
    f32x4 v[8];
#pragma unroll
    for (int u = 0; u < 8; ++u)
        v[u] = *(const f32x4*)(xp + (8 * tg + u) * Fc + 4 * fq);

    // ---- stage w_res as bf16 A-fragments (explicit slot, verified) ----
    // unit u=(row=u>>3, k8=u&7) holds w_res[row][8k8..8k8+7];
    // slot = (2*(row>>4) + (k8>>2))*64 + (k8&3)*16 + (row&15); read is linear.
#pragma unroll
    for (int i = 0; i < 2; ++i) {
        const int u   = tid + 256 * i;         // 0..511
        const int row = u >> 3;
        const int k8  = u & 7;
        f32x4 a0 = f32x4{0.f, 0.f, 0.f, 0.f};
        f32x4 a1 = f32x4{0.f, 0.f, 0.f, 0.f};
        if (row < Sc) {
            const float* wr = w_res + row * Tc + 8 * k8;
            a0 = *(const f32x4*)(wr);
            a1 = *(const f32x4*)(wr + 4);
        }
        const unsigned p0 = cvt_pk_bf16(a0.x, a0.y);
        const unsigned p1 = cvt_pk_bf16(a0.z, a0.w);
        const unsigned p2 = cvt_pk_bf16(a1.x, a1.y);
        const unsigned p3 = cvt_pk_bf16(a1.z, a1.w);
        const int slot = ((row >> 4) * 2 + (k8 >> 2)) * 64 + (k8 & 3) * 16 + (row & 15);
        *(i32x4*)(lds_a + slot * 16) = i32x4{(int)p0, (int)p1, (int)p2, (int)p3};
    }

    // ---- xT writes: 4 x ds_write_b128, swizzle t~ = t ^ 8*((f>>2)&3) ----
    // thread's swz = fq&3 for all 4 of its f's; t-base 8*tg -> 8*(tg^swz).
    const int tsw = 8 * (tg ^ (fq & 3));
#pragma unroll
    for (int fj = 0; fj < 4; ++fj) {
        const unsigned p0 = cvt_pk_bf16(v[0][fj], v[1][fj]);
        const unsigned p1 = cvt_pk_bf16(v[2][fj], v[3][fj]);
        const unsigned p2 = cvt_pk_bf16(v[4][fj], v[5][fj]);
        const unsigned p3 = cvt_pk_bf16(v[6][fj], v[7][fj]);
        *(i32x4*)(lds_base + ((4 * fq + fj) * LDSTW + tsw) * 2) =
            i32x4{(int)p0, (int)p1, (int)p2, (int)p3};
    }

    // ---- acc init = b_res[row] (C-operand); clamp tail (rows>=62 masked) ----
    f32x4 acc[4][2];
#pragma unroll
    for (int rt = 0; rt < 4; ++rt) {
        f32x4 bv;
#pragma unroll
        for (int j = 0; j < 4; ++j) {
            const int idx = 16 * rt + 4 * g + j;
            bv[j] = b_res[idx < Sc ? idx : Sc - 1];
        }
        acc[rt][0] = bv;
        acc[rt][1] = bv;
    }

    __syncthreads();

    // ---- A fragments from LDS (linear b128, conflict-free) ----
    short8 A[4][2];
#pragma unroll
    for (int rt = 0; rt < 4; ++rt)
#pragma unroll
        for (int kt = 0; kt < 2; ++kt)
            A[rt][kt] = *(const short8*)(lds_a + ((rt * 2 + kt) * 64 + lane) * 16);

    // ---- B frags: one b128 each; MFMA 2kt x 2ct x 4rt ----
    const int col0 = 32 * w + r16;
    const int swz8 = 8 * (g ^ (r16 >> 2));     // sw(col) = r16>>2 for all our cols
#pragma unroll
    for (int kt = 0; kt < 2; ++kt) {
        short8 Bf[2];
#pragma unroll
        for (int ct = 0; ct < 2; ++ct)
            Bf[ct] = *(const short8*)(lds_base +
                        ((col0 + 16 * ct) * LDSTW + 32 * kt + swz8) * 2);
#pragma unroll
        for (int rt = 0; rt < 4; ++rt)
#pragma unroll
            for (int ct = 0; ct < 2; ++ct)
                acc[rt][ct] = __builtin_amdgcn_mfma_f32_16x16x32_bf16(
                    A[rt][kt], Bf[ct], acc[rt][ct], 0, 0, 0);
    }

    // ---- epilogue: taps via 2 x ds_read_b64 bf16; gate; store ----
    const int sw8 = 8 * (r16 >> 2);            // swizzle bits for tap addressing
    float* op = out + (size_t)bc * (Sc * Fc);
#pragma unroll
    for (int rt = 0; rt < 4; ++rt) {
        const int r0 = 16 * rt + 4 * g;
#pragma unroll
        for (int ct = 0; ct < 2; ++ct) {
            const int col = col0 + 16 * ct;
            const i32x2 d1 = *(const i32x2*)(lds_base + (col * LDSTW + (r0 ^ sw8)) * 2);
            const i32x2 d2 = *(const i32x2*)(lds_base + (col * LDSTW + ((r0 + 4) ^ sw8)) * 2);
            const float t0 = bf16_lo(d1.x);    // x[r0]
            const float t1 = bf16_hi(d1.x);    // x[r0+1]
            const float t2 = bf16_lo(d1.y);    // x[r0+2]
            const float t3 = bf16_hi(d1.y);    // x[r0+3]
            const float t4 = bf16_lo(d2.x);    // x[r0+4] (garbage if r0+4>=64: masked)
            const float t5 = bf16_hi(d2.x);    // x[r0+5]

#define GATE_OUT(reg, xa, xb)                                                     \
            if (r0 + (reg) < Sc) {                                                \
                const float xt  = fmaf((xa), wt0, fmaf((xb), wt1, bt));           \
                const float xsg = fmaf((xa), ws0, fmaf((xb), ws1, bs));           \
                const float e2  = __expf(2.0f * xt);                              \
                const float em  = __expf(-xsg);                                   \
                const float gate = (e2 - 1.0f) *                                  \
                    __builtin_amdgcn_rcpf((e2 + 1.0f) * (1.0f + em));             \
                op[(r0 + (reg)) * Fc + col] =                                     \
                    fmaf(gate + acc[rt][ct][reg], wo, bo);                        \
            }
            GATE_OUT(0, t0, t2)
            GATE_OUT(1, t1, t3)
            GATE_OUT(2, t2, t4)
            GATE_OUT(3, t3, t5)
#undef GATE_OUT
        }
    }
}

extern "C" void kernel_launch(void* const* d_in, const int* in_sizes, int n_in,
                              void* d_out, int out_size, void* d_ws, size_t ws_size,
                              hipStream_t stream)
{
    const float* x      = (const float*)d_in[0];
    const float* w_tanh = (const float*)d_in[1];
    const float* b_tanh = (const float*)d_in[2];
    const float* w_sig  = (const float*)d_in[3];
    const float* b_sig  = (const float*)d_in[4];
    const float* w_out  = (const float*)d_in[5];
    const float* b_out  = (const float*)d_in[6];
    const float* w_res  = (const float*)d_in[7];
    const float* b_res  = (const float*)d_in[8];
    // d_in[9] = dilation (==2) -> compile-time DIL.

    float* out = (float*)d_out;

    gated_mfma_kernel<<<Bc * Cc, 256, 0, stream>>>(
        x, w_tanh, b_tanh, w_sig, b_sig, w_out, b_out, w_res, b_res, out);
}